// Round 4
// 880.659 us; speedup vs baseline: 1.0592x; 1.0592x over previous
//
#include <hip/hip_runtime.h>
#include <math.h>

// GroupedExperts MoE: out = ragged_dot( silu(x@w1^T) * (x@w3^T) * prob , w2^T )
// E=8, D=2048, H=1408, T=16384. bf16 MFMA compute, fp32 accumulate.
// v5 = round-0 passing kernel with ONE change: gemm2 widened to BN=256
// (64 MFMA per wave per barrier-pair instead of 32). gemm13/prep/convert are
// byte-identical to the verified round-0 version. This doubles as the
// infra-vs-kernel discriminator for the round-1..3 container failures.

#define E_ 8
#define D_ 2048
#define H_ 1408
#define T_ 16384
#define MAX_TILES 136  // T/128 + E upper bound on ragged 128-row tiles

typedef unsigned short u16;
typedef __bf16 bf16x8 __attribute__((ext_vector_type(8)));
typedef float f32x4 __attribute__((ext_vector_type(4)));

__device__ __forceinline__ u16 f2bf(float f) {
  unsigned int u = __float_as_uint(f);
  u += 0x7fffu + ((u >> 16) & 1u);  // round-to-nearest-even
  return (u16)(u >> 16);
}

// async global->LDS, 16B per lane; LDS base must be wave-uniform (lane scatter
// is implicit: base + lane*16).
__device__ __forceinline__ void load16_to_lds(const u16* g, u16* l) {
  __builtin_amdgcn_global_load_lds(
      (const __attribute__((address_space(1))) unsigned int*)g,
      (__attribute__((address_space(3))) unsigned int*)l, 16, 0, 0);
}

// ---------------------------------------------------------------- prep ------
// Build ragged tile table: each entry = (expert, row0, row_count, 0).
__global__ void prep_kernel(const int* __restrict__ counts, int4* __restrict__ table) {
  if (blockIdx.x == 0 && threadIdx.x == 0) {
    int t = 0, off = 0;
    for (int e = 0; e < E_; ++e) {
      int n = counts[e];
      for (int r = 0; r < n && t < MAX_TILES; r += 128) {
        int rc = n - r; if (rc > 128) rc = 128;
        table[t++] = make_int4(e, off + r, rc, 0);
      }
      off += n;
    }
    for (; t < MAX_TILES; ++t) table[t] = make_int4(0, 0, 0, 0);
  }
}

// ---------------------------------------------------------- fp32 -> bf16 ----
__global__ void convert_kernel(const float4* __restrict__ src, ushort4* __restrict__ dst, int n4) {
  int i = blockIdx.x * 256 + threadIdx.x;
  if (i < n4) {
    float4 v = src[i];
    ushort4 o;
    o.x = f2bf(v.x); o.y = f2bf(v.y); o.z = f2bf(v.z); o.w = f2bf(v.w);
    dst[i] = o;
  }
}

// ------------------------------------------------------------- gemm13 -------
// C1 = X @ W1e^T, C3 = X @ W3e^T  (W stored [H][D], i.e. N x K, K-contiguous)
// h = silu(C1) * C3 * prob  -> bf16 Hb [T][H]
// Tile 128x128, BK=64, 4 waves each computing a 64x64 quadrant with 4x4
// 16x16x32 MFMA frags (x2 accumulators for the fused w1/w3 pair).
// LDS layout is MFMA-fragment-ordered: 16 units (m-block x k-chunk) of
// 64 lanes x 16B, so staging and ds_read_b128 are both lane-contiguous.
__global__ __launch_bounds__(256, 2) void gemm13_kernel(
    const u16* __restrict__ X, const u16* __restrict__ W1,
    const u16* __restrict__ W3, const float* __restrict__ prob,
    const int4* __restrict__ table, u16* __restrict__ Hb) {
  __shared__ __align__(16) u16 lA[16 * 512];
  __shared__ __align__(16) u16 lB1[16 * 512];
  __shared__ __align__(16) u16 lB3[16 * 512];

  const int4 te = table[blockIdx.x];
  const int e = te.x, row0 = te.y, rc = te.z;
  if (rc <= 0) return;
  const int n0 = blockIdx.y * 128;

  const int tid = threadIdx.x;
  const int lane = tid & 63;
  const int wv = tid >> 6;        // 0..3
  const int mh = wv >> 1, nh = wv & 1;
  const int lm = lane & 15;            // row within 16-block
  const int lk = (lane >> 4) << 3;     // k offset within 32-chunk

  const u16* W1e = W1 + (size_t)e * ((size_t)H_ * D_);
  const u16* W3e = W3 + (size_t)e * ((size_t)H_ * D_);

  const u16* aptr[4]; const u16* b1ptr[4]; const u16* b3ptr[4];
#pragma unroll
  for (int i = 0; i < 4; ++i) {
    int uu = wv * 4 + i, mb = uu >> 1, kc = uu & 1;
    int ar = row0 + mb * 16 + lm; if (ar > T_ - 1) ar = T_ - 1;  // clamp: masked at store
    int col = kc * 32 + lk;
    aptr[i]  = X   + (size_t)ar * D_ + col;
    b1ptr[i] = W1e + (size_t)(n0 + mb * 16 + lm) * D_ + col;
    b3ptr[i] = W3e + (size_t)(n0 + mb * 16 + lm) * D_ + col;
  }

  const f32x4 zero = {0.f, 0.f, 0.f, 0.f};
  f32x4 acc1[4][4], acc3[4][4];
#pragma unroll
  for (int i = 0; i < 4; ++i)
#pragma unroll
    for (int j = 0; j < 4; ++j) { acc1[i][j] = zero; acc3[i][j] = zero; }

  for (int k0 = 0; k0 < D_; k0 += 64) {
    __syncthreads();
#pragma unroll
    for (int i = 0; i < 4; ++i) {
      int uu = wv * 4 + i;
      load16_to_lds(aptr[i],  &lA[uu * 512]);
      load16_to_lds(b1ptr[i], &lB1[uu * 512]);
      load16_to_lds(b3ptr[i], &lB3[uu * 512]);
      aptr[i] += 64; b1ptr[i] += 64; b3ptr[i] += 64;
    }
    __syncthreads();
#pragma unroll
    for (int kc = 0; kc < 2; ++kc) {
      bf16x8 af[4], bf1[4], bf3[4];
#pragma unroll
      for (int i = 0; i < 4; ++i)
        af[i] = *(const bf16x8*)&lA[((mh * 4 + i) * 2 + kc) * 512 + lane * 8];
#pragma unroll
      for (int j = 0; j < 4; ++j) {
        bf1[j] = *(const bf16x8*)&lB1[((nh * 4 + j) * 2 + kc) * 512 + lane * 8];
        bf3[j] = *(const bf16x8*)&lB3[((nh * 4 + j) * 2 + kc) * 512 + lane * 8];
      }
#pragma unroll
      for (int i = 0; i < 4; ++i)
#pragma unroll
        for (int j = 0; j < 4; ++j) {
          acc1[i][j] = __builtin_amdgcn_mfma_f32_16x16x32_bf16(af[i], bf1[j], acc1[i][j], 0, 0, 0);
          acc3[i][j] = __builtin_amdgcn_mfma_f32_16x16x32_bf16(af[i], bf3[j], acc3[i][j], 0, 0, 0);
        }
    }
  }

  // epilogue: C/D mapping col = lane&15, row = (lane>>4)*4 + reg  [m89/m91]
  const int quad = lane >> 4, cl = lane & 15;
#pragma unroll
  for (int i = 0; i < 4; ++i) {
#pragma unroll
    for (int r = 0; r < 4; ++r) {
      int rit = mh * 64 + i * 16 + quad * 4 + r;
      if (rit < rc) {
        int rowg = row0 + rit;
        float p = prob[rowg];
        size_t base = (size_t)rowg * H_ + n0 + nh * 64 + cl;
#pragma unroll
        for (int j = 0; j < 4; ++j) {
          float v1 = acc1[i][j][r], v3 = acc3[i][j][r];
          float hv = (v1 / (1.f + __expf(-v1))) * v3 * p;
          Hb[base + j * 16] = f2bf(hv);
        }
      }
    }
  }
}

// ------------------------------------------------------------- gemm2 --------
// Out = Hb @ W2e^T, W2 stored [D][H] (N x K, K-contiguous). K=1408=22*64.
// v5: tile 128x256 (BN=256), BK=64, 256 threads (4 waves as 2M x 2N, each
// 64x128 out, acc[4][8]). 64 MFMA per wave per K-step -> 2x barrier
// amortization vs round-0's 32. LDS 48KB single-buffer, fragment-ordered.
__global__ __launch_bounds__(256, 2) void gemm2_kernel(
    const u16* __restrict__ Hb, const u16* __restrict__ W2,
    const int4* __restrict__ table, float* __restrict__ Out) {
  __shared__ __align__(16) u16 lA[16 * 512];   // 128 rows x 64 k
  __shared__ __align__(16) u16 lB[32 * 512];   // 256 cols x 64 k

  const int4 te = table[blockIdx.x];
  const int e = te.x, row0 = te.y, rc = te.z;
  if (rc <= 0) return;
  const int n0 = blockIdx.y * 256;

  const int tid = threadIdx.x;
  const int lane = tid & 63;
  const int wv = tid >> 6;        // 0..3
  const int wm = wv >> 1;         // 0..1 -> rows wm*64
  const int wn = wv & 1;          // 0..1 -> cols wn*128
  const int lm = lane & 15;
  const int lk = (lane >> 4) << 3;

  const u16* W2e = W2 + (size_t)e * ((size_t)D_ * H_);

  // staging: wave stages A units wv*4+i (i<4, 16 total) and B units wv*8+i
  // (i<8, 32 total). unit = 64 lanes x 16B, unit index = (row16blk)*2 + kc.
  const u16* aptr[4]; const u16* bptr[8];
#pragma unroll
  for (int i = 0; i < 4; ++i) {
    int uu = wv * 4 + i, mb = uu >> 1, kc = uu & 1;
    int ar = row0 + mb * 16 + lm; if (ar > T_ - 1) ar = T_ - 1;  // masked at store
    aptr[i] = Hb + (size_t)ar * H_ + kc * 32 + lk;
  }
#pragma unroll
  for (int i = 0; i < 8; ++i) {
    int uu = wv * 8 + i, nb = uu >> 1, kc = uu & 1;
    bptr[i] = W2e + (size_t)(n0 + nb * 16 + lm) * H_ + kc * 32 + lk;
  }

  const f32x4 zero = {0.f, 0.f, 0.f, 0.f};
  f32x4 acc[4][8];
#pragma unroll
  for (int i = 0; i < 4; ++i)
#pragma unroll
    for (int j = 0; j < 8; ++j) acc[i][j] = zero;

  for (int k0 = 0; k0 < H_; k0 += 64) {
    __syncthreads();
#pragma unroll
    for (int i = 0; i < 4; ++i) {
      load16_to_lds(aptr[i], &lA[(wv * 4 + i) * 512]);
      aptr[i] += 64;
    }
#pragma unroll
    for (int i = 0; i < 8; ++i) {
      load16_to_lds(bptr[i], &lB[(wv * 8 + i) * 512]);
      bptr[i] += 64;
    }
    __syncthreads();
#pragma unroll
    for (int kc = 0; kc < 2; ++kc) {
      bf16x8 af[4], bb[8];
#pragma unroll
      for (int i = 0; i < 4; ++i)
        af[i] = *(const bf16x8*)&lA[((wm * 4 + i) * 2 + kc) * 512 + lane * 8];
#pragma unroll
      for (int j = 0; j < 8; ++j)
        bb[j] = *(const bf16x8*)&lB[((wn * 8 + j) * 2 + kc) * 512 + lane * 8];
#pragma unroll
      for (int i = 0; i < 4; ++i)
#pragma unroll
        for (int j = 0; j < 8; ++j)
          acc[i][j] = __builtin_amdgcn_mfma_f32_16x16x32_bf16(af[i], bb[j], acc[i][j], 0, 0, 0);
    }
  }

  const int quad = lane >> 4, cl = lane & 15;
#pragma unroll
  for (int i = 0; i < 4; ++i) {
#pragma unroll
    for (int r = 0; r < 4; ++r) {
      int rit = wm * 64 + i * 16 + quad * 4 + r;
      if (rit < rc) {
        size_t base = (size_t)(row0 + rit) * D_ + n0 + wn * 128 + cl;
#pragma unroll
        for (int j = 0; j < 8; ++j) Out[base + j * 16] = acc[i][j][r];
      }
    }
  }
}

// ------------------------------------------------------------ launch --------
extern "C" void kernel_launch(void* const* d_in, const int* in_sizes, int n_in,
                              void* d_out, int out_size, void* d_ws, size_t ws_size,
                              hipStream_t stream) {
  const float* x    = (const float*)d_in[0];
  const float* w1   = (const float*)d_in[1];
  const float* w2   = (const float*)d_in[2];
  const float* w3   = (const float*)d_in[3];
  const float* prob = (const float*)d_in[4];
  const int* counts = (const int*)d_in[5];
  float* out = (float*)d_out;

  char* ws = (char*)d_ws;
  const size_t XB = (size_t)T_ * D_ * 2;       // x bf16       67,108,864 B
  const size_t WB = (size_t)E_ * H_ * D_ * 2;  // each w bf16  46,137,344 B
  const size_t HB = (size_t)T_ * H_ * 2;       // h bf16       46,137,344 B
  u16* xb  = (u16*)(ws);
  u16* w1b = (u16*)(ws + XB);
  u16* w3b = (u16*)(ws + XB + WB);
  u16* w2b = (u16*)(ws + XB + 2 * WB);
  u16* hb  = (u16*)(ws + XB + 3 * WB);
  int4* table = (int4*)(ws + XB + 3 * WB + HB);
  // total ws use: ~251.7 MB

  prep_kernel<<<1, 1, 0, stream>>>(counts, table);

  int n4x = T_ * D_ / 4;
  convert_kernel<<<(n4x + 255) / 256, 256, 0, stream>>>((const float4*)x, (ushort4*)xb, n4x);
  int n4w = E_ * H_ * D_ / 4;
  convert_kernel<<<(n4w + 255) / 256, 256, 0, stream>>>((const float4*)w1, (ushort4*)w1b, n4w);
  convert_kernel<<<(n4w + 255) / 256, 256, 0, stream>>>((const float4*)w3, (ushort4*)w3b, n4w);
  convert_kernel<<<(n4w + 255) / 256, 256, 0, stream>>>((const float4*)w2, (ushort4*)w2b, n4w);

  gemm13_kernel<<<dim3(MAX_TILES, H_ / 128), 256, 0, stream>>>(xb, w1b, w3b, prob, table, hb);
  gemm2_kernel<<<dim3(MAX_TILES, D_ / 256), 256, 0, stream>>>(hb, w2b, table, out);
}